// Round 14
// baseline (392.793 us; speedup 1.0000x reference)
//
#include <hip/hip_runtime.h>

#define NN 100000
#define NNPAD 100352   // 196*512 = 16*6272
#define NE 1600000
#define NG 64
#define DI 128
#define DH 256
#define DO 128
#define SEG2 25088     // cmT s-segment per block (~100 KB LDS), NNPAD = 4*SEG2
#define NPART 16
#define PSTRIDE 6272   // dst range per partition
#define PCAP 110000    // partition capacity (mean 100K, sd ~307 -> 32 sigma slack)
#define SUBR 784       // dsts per count/place block (PSTRIDE/8)

using short8 = __attribute__((ext_vector_type(8))) short;
using f32x4  = __attribute__((ext_vector_type(4))) float;

__device__ __forceinline__ float bf2f(unsigned short u) {
    return __uint_as_float(((unsigned)u) << 16);
}
__device__ __forceinline__ unsigned short f2bf(float f) {
    unsigned u = __float_as_uint(f);
    unsigned r = (u + 0x7FFFu + ((u >> 16) & 1u)) >> 16;   // RNE
    return (unsigned short)r;
}

// ---------------- prep: x -> bf16, W1 -> w1t, partition cursor init ----------------
__global__ void k_prep(const float* __restrict__ x, unsigned short* __restrict__ xbf,
                       const float* __restrict__ W1, unsigned short* __restrict__ w1t,
                       int* __restrict__ pcur) {
    int i = blockIdx.x * blockDim.x + threadIdx.x;
    const int NX4 = NN * 32;
    if (i < NX4) {
        float4 v = ((const float4*)x)[i];
        ushort4 o;
        o.x = f2bf(v.x); o.y = f2bf(v.y); o.z = f2bf(v.z); o.w = f2bf(v.w);
        ((ushort4*)xbf)[i] = o;
    } else if (i < NX4 + DI * DH) {
        int t = i - NX4;
        int k = t / DH, n = t % DH;
        w1t[n * DI + k] = f2bf(W1[t]);
    }
    if (i < NPART) pcur[i] = i * PCAP;
}

// ---------------- radix partition of edges by dst range ----------------
__global__ __launch_bounds__(256) void k_partition(const int* __restrict__ src,
        const int* __restrict__ dst, int* __restrict__ pcur,
        int* __restrict__ ps, int* __restrict__ pd, int e) {
    __shared__ int hist[NPART];
    __shared__ int curb[NPART];
    const int EPT = 16;
    int t = threadIdx.x;
    if (t < NPART) hist[t] = 0;
    __syncthreads();
    int base = blockIdx.x * (256 * EPT) + t;
    int sA[EPT], dA[EPT];
#pragma unroll
    for (int k = 0; k < EPT; ++k) {
        int i = base + k * 256;
        if (i < e) {
            sA[k] = src[i]; dA[k] = dst[i];
            atomicAdd(&hist[dA[k] / PSTRIDE], 1);
        } else dA[k] = -1;
    }
    __syncthreads();
    if (t < NPART) curb[t] = atomicAdd(&pcur[t], hist[t]);
    __syncthreads();
#pragma unroll
    for (int k = 0; k < EPT; ++k) {
        if (dA[k] >= 0) {
            int b = dA[k] / PSTRIDE;
            int pos = atomicAdd(&curb[b], 1);   // LDS cursor, global position
            ps[pos] = sA[k];
            pd[pos] = dA[k];
        }
    }
}

// ---------------- per-subrange degree count (no global atomics) ----------------
__global__ __launch_bounds__(256) void k_count(const int* __restrict__ pd,
        const int* __restrict__ pcur, int* __restrict__ cnt) {
    __shared__ int c[SUBR];
    int b = blockIdx.x;                 // 128 blocks
    int p = b >> 3, sb = b & 7;
    int lo = p * PSTRIDE + sb * SUBR;
    int t = threadIdx.x;
    for (int i = t; i < SUBR; i += 256) c[i] = 0;
    __syncthreads();
    int j0 = p * PCAP, j1 = pcur[p];
    int j = j0 + t;
    for (; j + 768 < j1; j += 1024) {
        int a0 = pd[j] - lo, a1 = pd[j + 256] - lo;
        int a2 = pd[j + 512] - lo, a3 = pd[j + 768] - lo;
        if ((unsigned)a0 < SUBR) atomicAdd(&c[a0], 1);
        if ((unsigned)a1 < SUBR) atomicAdd(&c[a1], 1);
        if ((unsigned)a2 < SUBR) atomicAdd(&c[a2], 1);
        if ((unsigned)a3 < SUBR) atomicAdd(&c[a3], 1);
    }
    for (; j < j1; j += 256) {
        int a = pd[j] - lo;
        if ((unsigned)a < SUBR) atomicAdd(&c[a], 1);
    }
    __syncthreads();
    for (int i = t; i < SUBR; i += 256) {
        int d = lo + i;
        if (d < NN) cnt[d] = c[i];
    }
}

// ---------------- exclusive scan (2-level) ----------------

__global__ void k_scan1(const int* __restrict__ in, int* __restrict__ out,
                        int* __restrict__ bsum, int n) {
    __shared__ int sh[256];
    int t = threadIdx.x;
    int i = blockIdx.x * 256 + t;
    int v = (i < n) ? in[i] : 0;
    sh[t] = v;
    __syncthreads();
    for (int off = 1; off < 256; off <<= 1) {
        int add = (t >= off) ? sh[t - off] : 0;
        __syncthreads();
        sh[t] += add;
        __syncthreads();
    }
    if (i < n) out[i] = sh[t] - v;
    if (t == 255) bsum[blockIdx.x] = sh[255];
}
__global__ void k_scan2(int* __restrict__ bsum, int* __restrict__ cntg, int nb) {
    __shared__ int sh[512];
    int t = threadIdx.x;
    if (t < NG) cntg[t] = 0;
    int v = (t < nb) ? bsum[t] : 0;
    sh[t] = v;
    __syncthreads();
    for (int off = 1; off < 512; off <<= 1) {
        int add = (t >= off) ? sh[t - off] : 0;
        __syncthreads();
        sh[t] += add;
        __syncthreads();
    }
    if (t < nb) bsum[t] = sh[t] - v;
}
// finalize rowst, dinv, gdv, per-graph counts
__global__ void k_scan3(int* __restrict__ rowst, const int* __restrict__ bsum,
                        const int* __restrict__ deg, float* __restrict__ dinv,
                        const int* __restrict__ batch, int2* __restrict__ gdv,
                        int* __restrict__ cntg, int n, int total) {
    __shared__ int sh[NG];
    int t = threadIdx.x;
    if (t < NG) sh[t] = 0;
    __syncthreads();
    int i = blockIdx.x * 256 + t;
    if (i < n) {
        float dv = rsqrtf((float)(deg[i] + 1));
        dinv[i] = dv;
        int b = batch[i];
        int2 g; g.x = __float_as_int(dv); g.y = b;
        gdv[i] = g;
        atomicAdd(&sh[b], 1);
        rowst[i] += bsum[blockIdx.x];
    }
    if (i == 0) rowst[n] = total;
    __syncthreads();
    if (t < NG && sh[t]) atomicAdd(&cntg[t], sh[t]);
}

// ---------------- place: LDS-cursor CSR fill (no global atomics) ----------------
__global__ __launch_bounds__(256) void k_place(const int* __restrict__ ps,
        const int* __restrict__ pd, const int* __restrict__ pcur,
        const int* __restrict__ rowst, const float* __restrict__ dinv,
        int2* __restrict__ csr8) {
    __shared__ int cur[SUBR];
    __shared__ float dl[SUBR];
    int b = blockIdx.x;
    int p = b >> 3, sb = b & 7;
    int lo = p * PSTRIDE + sb * SUBR;
    int t = threadIdx.x;
    for (int i = t; i < SUBR; i += 256) {
        int d = lo + i;
        cur[i] = (d < NN) ? rowst[d] : 0;
        dl[i]  = (d < NN) ? dinv[d] : 0.f;
    }
    __syncthreads();
    int j0 = p * PCAP, j1 = pcur[p];
    int j = j0 + t;
    for (; j + 768 < j1; j += 1024) {
        int d0 = pd[j], d1 = pd[j + 256], d2 = pd[j + 512], d3 = pd[j + 768];
        int s0 = ps[j], s1 = ps[j + 256], s2 = ps[j + 512], s3 = ps[j + 768];
        int a0 = d0 - lo, a1 = d1 - lo, a2 = d2 - lo, a3 = d3 - lo;
        if ((unsigned)a0 < SUBR) {
            float w = dinv[s0] * dl[a0];
            int pos = atomicAdd(&cur[a0], 1);
            csr8[pos] = make_int2(s0, __float_as_int(w));
        }
        if ((unsigned)a1 < SUBR) {
            float w = dinv[s1] * dl[a1];
            int pos = atomicAdd(&cur[a1], 1);
            csr8[pos] = make_int2(s1, __float_as_int(w));
        }
        if ((unsigned)a2 < SUBR) {
            float w = dinv[s2] * dl[a2];
            int pos = atomicAdd(&cur[a2], 1);
            csr8[pos] = make_int2(s2, __float_as_int(w));
        }
        if ((unsigned)a3 < SUBR) {
            float w = dinv[s3] * dl[a3];
            int pos = atomicAdd(&cur[a3], 1);
            csr8[pos] = make_int2(s3, __float_as_int(w));
        }
    }
    for (; j < j1; j += 256) {
        int d = pd[j];
        int a = d - lo;
        if ((unsigned)a < SUBR) {
            int s = ps[j];
            float w = dinv[s] * dl[a];
            int pos = atomicAdd(&cur[a], 1);
            csr8[pos] = make_int2(s, __float_as_int(w));
        }
    }
}

// ---------------- cmT build: flat streaming over per-graph contiguous (s,w) pairs ----------------
__global__ __launch_bounds__(256) void k_cmbuild(const int2* __restrict__ csr8,
        const int* __restrict__ rowst, const int* __restrict__ batch,
        const int2* __restrict__ gdv, float* __restrict__ cmT) {
    __shared__ float acc[SEG2];          // ~100 KB
    int g   = blockIdx.x >> 2;
    int seg = blockIdx.x & 3;
    int slo = seg * SEG2;
    int t = threadIdx.x;
    for (int i = t; i < SEG2; i += 256) acc[i] = 0.f;

    int lo = 0, hi = NN;
    while (lo < hi) { int m = (lo + hi) >> 1; if (batch[m] < g) lo = m + 1; else hi = m; }
    int dstart = lo;
    int lo2 = lo, hi2 = NN;
    while (lo2 < hi2) { int m = (lo2 + hi2) >> 1; if (batch[m] < g + 1) lo2 = m + 1; else hi2 = m; }
    int e0 = rowst[dstart], e1 = rowst[lo2];
    __syncthreads();

    int j = e0 + t;
    for (; j + 768 < e1; j += 1024) {
        int2 p0 = csr8[j];
        int2 p1 = csr8[j + 256];
        int2 p2 = csr8[j + 512];
        int2 p3 = csr8[j + 768];
        int a0 = p0.x - slo, a1 = p1.x - slo, a2 = p2.x - slo, a3 = p3.x - slo;
        if ((unsigned)a0 < SEG2) atomicAdd(&acc[a0], __int_as_float(p0.y));
        if ((unsigned)a1 < SEG2) atomicAdd(&acc[a1], __int_as_float(p1.y));
        if ((unsigned)a2 < SEG2) atomicAdd(&acc[a2], __int_as_float(p2.y));
        if ((unsigned)a3 < SEG2) atomicAdd(&acc[a3], __int_as_float(p3.y));
    }
    for (; j < e1; j += 256) {
        int2 p = csr8[j];
        int a = p.x - slo;
        if ((unsigned)a < SEG2) atomicAdd(&acc[a], __int_as_float(p.y));
    }
    __syncthreads();

    float* row = cmT + (size_t)g * NNPAD;
    for (int i = t; i < SEG2; i += 256) {
        int s = slo + i;
        float v = acc[i];
        if (s < NN) {
            int2 gv = gdv[s];
            if (gv.y == g) { float dv = __int_as_float(gv.x); v += dv * dv; }
        }
        row[s] = v;
    }
}

// ---------------- layer-1 aggregation: weights streamed from packed CSR ----------------
__global__ __launch_bounds__(256) void k_agg16(const unsigned short* __restrict__ feat,
        const int2* __restrict__ csr8, const int* __restrict__ row_start,
        const float* __restrict__ dinv, unsigned short* __restrict__ out, int n) {
    int gid = blockIdx.x * blockDim.x + threadIdx.x;
    int node = gid >> 4;
    int lane = threadIdx.x & 15;
    if (node >= n) return;
    const short8* f8 = (const short8*)feat;
    float wd = dinv[node];
    float wd2 = wd * wd;
    short8 a = f8[(size_t)node * 16 + lane];
    float acc[8];
#pragma unroll
    for (int i = 0; i < 8; ++i) acc[i] = bf2f((unsigned short)a[i]) * wd2;
    int j = row_start[node], end = row_start[node + 1];
    for (; j + 3 < end; j += 4) {
        int2 p0 = csr8[j], p1 = csr8[j + 1], p2 = csr8[j + 2], p3 = csr8[j + 3];
        float w0 = __int_as_float(p0.y), w1 = __int_as_float(p1.y);
        float w2 = __int_as_float(p2.y), w3 = __int_as_float(p3.y);
        short8 v0 = f8[(size_t)p0.x * 16 + lane];
        short8 v1 = f8[(size_t)p1.x * 16 + lane];
        short8 v2 = f8[(size_t)p2.x * 16 + lane];
        short8 v3 = f8[(size_t)p3.x * 16 + lane];
#pragma unroll
        for (int i = 0; i < 8; ++i)
            acc[i] += w0 * bf2f((unsigned short)v0[i]) + w1 * bf2f((unsigned short)v1[i])
                    + w2 * bf2f((unsigned short)v2[i]) + w3 * bf2f((unsigned short)v3[i]);
    }
    for (; j < end; ++j) {
        int2 p = csr8[j];
        float w = __int_as_float(p.y);
        short8 v = f8[(size_t)p.x * 16 + lane];
#pragma unroll
        for (int i = 0; i < 8; ++i) acc[i] += w * bf2f((unsigned short)v[i]);
    }
    short8 o;
#pragma unroll
    for (int i = 0; i < 8; ++i) o[i] = (short)f2bf(acc[i]);
    ((short8*)out)[(size_t)node * 16 + lane] = o;
}

// ---------------- fused: h1-chunk MFMA (LDS) + pre-partial MFMA ----------------
__global__ __launch_bounds__(512) void k_fused(const unsigned short* __restrict__ agg1,
        const unsigned short* __restrict__ w1t, const float* __restrict__ b1,
        const float* __restrict__ cmT, float* __restrict__ partial) {
    __shared__ unsigned short Ws[256 * 128];  // 64 KB
    __shared__ unsigned short As[64 * 128];   // 16 KB
    __shared__ unsigned short Hs[256 * 64];   // 32 KB
    __shared__ unsigned short Cs[64 * 64];    // 8 KB

    const int tid = threadIdx.x;
    const int sb = blockIdx.x * 512;

#pragma unroll
    for (int i = 0; i < 8; ++i) {
        int c = tid + i * 512;
        int row = c >> 4, seg = c & 15;
        uint4 v = *(const uint4*)(w1t + row * 128 + seg * 8);
        *(uint4*)((char*)Ws + row * 256 + ((seg * 16) ^ ((row & 7) << 4))) = v;
    }

    const int w  = tid >> 6;
    const int l  = tid & 63;
    const int lr = l & 15;
    const int lg = l >> 4;
    const int swz = (lr & 7) << 4;
    const int j0 = w * 32;

    float bb0 = b1[j0 + lr];
    float bb1 = b1[j0 + 16 + lr];

    f32x4 acc2[4][2] = {};

    for (int c = 0; c < 8; ++c) {
        int s0 = sb + c * 64;
        __syncthreads();
#pragma unroll
        for (int i = 0; i < 2; ++i) {
            int cc = tid + i * 512;
            int row = cc >> 4, seg = cc & 15;
            uint4 v = make_uint4(0, 0, 0, 0);
            int node = s0 + row;
            if (node < NN) v = *(const uint4*)(agg1 + (size_t)node * 128 + seg * 8);
            *(uint4*)((char*)As + row * 256 + ((seg * 16) ^ ((row & 7) << 4))) = v;
        }
        {
            int g = tid >> 3, seg = tid & 7;
            const float* cp = cmT + (size_t)g * NNPAD + s0 + seg * 8;
            float4 f0 = *(const float4*)cp;
            float4 f1 = *(const float4*)(cp + 4);
            uint4 v;
            v.x = (unsigned)f2bf(f0.x) | ((unsigned)f2bf(f0.y) << 16);
            v.y = (unsigned)f2bf(f0.z) | ((unsigned)f2bf(f0.w) << 16);
            v.z = (unsigned)f2bf(f1.x) | ((unsigned)f2bf(f1.y) << 16);
            v.w = (unsigned)f2bf(f1.z) | ((unsigned)f2bf(f1.w) << 16);
            *(uint4*)((char*)Cs + g * 128 + ((seg * 16) ^ ((g & 7) << 4))) = v;
        }
        __syncthreads();

        // phase A: h1 chunk = relu(agg1c @ w1t^T + b1), K=128
        f32x4 accA[4][2] = {};
#pragma unroll
        for (int ks = 0; ks < 4; ++ks) {
            int kb = ks * 64 + lg * 16;
            short8 a[4];
#pragma unroll
            for (int m = 0; m < 4; ++m)
                a[m] = *(const short8*)((const char*)As + (m * 16 + lr) * 256 + (kb ^ swz));
#pragma unroll
            for (int n = 0; n < 2; ++n) {
                short8 b = *(const short8*)((const char*)Ws + (j0 + n * 16 + lr) * 256 + (kb ^ swz));
#pragma unroll
                for (int m = 0; m < 4; ++m)
                    accA[m][n] = __builtin_amdgcn_mfma_f32_16x16x32_bf16(a[m], b, accA[m][n], 0, 0, 0);
            }
        }
#pragma unroll
        for (int n = 0; n < 2; ++n) {
            int j = j0 + n * 16 + lr;
            float bbv = n ? bb1 : bb0;
#pragma unroll
            for (int m = 0; m < 4; ++m) {
                float v0 = fmaxf(accA[m][n][0] + bbv, 0.f);
                float v1 = fmaxf(accA[m][n][1] + bbv, 0.f);
                float v2 = fmaxf(accA[m][n][2] + bbv, 0.f);
                float v3 = fmaxf(accA[m][n][3] + bbv, 0.f);
                uint2 p;
                p.x = (unsigned)f2bf(v0) | ((unsigned)f2bf(v1) << 16);
                p.y = (unsigned)f2bf(v2) | ((unsigned)f2bf(v3) << 16);
                *(uint2*)((char*)Hs + j * 128 + (((m * 16 + lg * 4) * 2) ^ swz)) = p;
            }
        }
        __syncthreads();

        // phase B: acc2[g][j] += Cs @ Hs^T, K=64
#pragma unroll
        for (int ks = 0; ks < 2; ++ks) {
            int kb = ks * 64 + lg * 16;
            short8 a[4];
#pragma unroll
            for (int mg = 0; mg < 4; ++mg)
                a[mg] = *(const short8*)((const char*)Cs + (mg * 16 + lr) * 128 + (kb ^ swz));
#pragma unroll
            for (int n = 0; n < 2; ++n) {
                short8 b = *(const short8*)((const char*)Hs + (j0 + n * 16 + lr) * 128 + (kb ^ swz));
#pragma unroll
                for (int mg = 0; mg < 4; ++mg)
                    acc2[mg][n] = __builtin_amdgcn_mfma_f32_16x16x32_bf16(a[mg], b, acc2[mg][n], 0, 0, 0);
            }
        }
    }

    float* pb = partial + (size_t)blockIdx.x * (NG * DH);
#pragma unroll
    for (int mg = 0; mg < 4; ++mg)
#pragma unroll
        for (int n = 0; n < 2; ++n)
#pragma unroll
            for (int r = 0; r < 4; ++r) {
                int g = mg * 16 + lg * 4 + r;
                int j = j0 + n * 16 + lr;
                pb[g * DH + j] = acc2[mg][n][r];
            }
}

// ---------------- tail: reduce 196 partials + final 64x256x128 GEMM ----------------
__global__ __launch_bounds__(256) void k_tail(const float* __restrict__ partial,
        const float* __restrict__ W2, const float* __restrict__ b2,
        const int* __restrict__ cntg, float* __restrict__ out) {
    __shared__ float pre[DH];
    int g = blockIdx.x;
    int t = threadIdx.x;
    float s0 = 0.f, s1 = 0.f, s2 = 0.f, s3 = 0.f;
    for (int b = 0; b < 196; b += 4) {
        s0 += partial[(size_t)b * (NG * DH) + g * DH + t];
        s1 += partial[(size_t)(b + 1) * (NG * DH) + g * DH + t];
        s2 += partial[(size_t)(b + 2) * (NG * DH) + g * DH + t];
        s3 += partial[(size_t)(b + 3) * (NG * DH) + g * DH + t];
    }
    pre[t] = (s0 + s1) + (s2 + s3);
    __syncthreads();
    if (t < DO) {
        float acc = (float)cntg[g] * b2[t];
        for (int k = 0; k < DH; ++k)
            acc = fmaf(pre[k], W2[k * DO + t], acc);
        out[g * DO + t] = acc;
    }
}

// ---------------- launch ----------------

extern "C" void kernel_launch(void* const* d_in, const int* in_sizes, int n_in,
                              void* d_out, int out_size, void* d_ws, size_t ws_size,
                              hipStream_t stream) {
    const float* x     = (const float*)d_in[0];
    const int*   ei    = (const int*)d_in[1];
    const int*   batch = (const int*)d_in[2];
    const float* W1    = (const float*)d_in[3];
    const float* b1    = (const float*)d_in[4];
    const float* W2    = (const float*)d_in[5];
    const float* b2    = (const float*)d_in[6];
    float* out = (float*)d_out;

    const int* src = ei;
    const int* dst = ei + NE;

    // workspace layout, peak ~119 MB
    char* ws = (char*)d_ws;
    float*          dinv    = (float*)(ws + 0);                  // 400 KB
    int*            cnt_in  = (int*)(ws + 524288);               // degree counts
    int*            rowst   = (int*)(ws + 1048576);              // NN+1
    int*            bsum    = (int*)(ws + 1572864);
    int*            cntg    = (int*)(ws + 1576960);
    unsigned short* w1t     = (unsigned short*)(ws + 1577216);   // 64 KB
    int2*           gdv     = (int2*)(ws + 1642752);             // 800 KB
    int2*           csr8    = (int2*)(ws + 2443264);             // 12.8 MB
    unsigned short* xbf     = (unsigned short*)(ws + 15243264);  // 25.6 MB
    unsigned short* agg1    = (unsigned short*)(ws + 40843264);  // 25.6 MB
    float*          cmT     = (float*)(ws + 66443264);           // 25.69 MB
    float*          partial = (float*)(ws + 92133376);           // 12.85 MB
    int*            ps      = (int*)(ws + 104986624);            // 7.04 MB
    int*            pd      = (int*)(ws + 112026624);            // 7.04 MB
    int*            pcur    = (int*)(ws + 119066624);            // 64 B

    const int BLK = 256;
    auto cdiv = [](int a, int b) { return (a + b - 1) / b; };
    const int NB = cdiv(NN, 256);   // 391

    // ---- prep (cvt + wt + pcur init) ----
    k_prep<<<cdiv(NN * 32 + DI * DH, BLK), BLK, 0, stream>>>(x, xbf, W1, w1t, pcur);

    // ---- radix partition edges by dst range ----
    k_partition<<<cdiv(NE, 256 * 16), 256, 0, stream>>>(src, dst, pcur, ps, pd, NE);

    // ---- per-subrange degree count (LDS, no global atomics) ----
    k_count<<<NPART * 8, 256, 0, stream>>>(pd, pcur, cnt_in);

    // ---- scan (+ dinv/gdv/graph-counts) ----
    k_scan1<<<NB, 256, 0, stream>>>(cnt_in, rowst, bsum, NN);
    k_scan2<<<1, 512, 0, stream>>>(bsum, cntg, NB);
    k_scan3<<<NB, 256, 0, stream>>>(rowst, bsum, cnt_in, dinv, batch, gdv, cntg, NN, NE);

    // ---- place: CSR fill via LDS cursors ----
    k_place<<<NPART * 8, 256, 0, stream>>>(ps, pd, pcur, rowst, dinv, csr8);

    // ---- cmT from packed CSR (flat streaming, LDS-accumulated) ----
    k_cmbuild<<<NG * 4, 256, 0, stream>>>(csr8, rowst, batch, gdv, cmT);

    // ---- layer 1 aggregation ----
    k_agg16<<<cdiv(NN * 16, BLK), BLK, 0, stream>>>(xbf, csr8, rowst, dinv, agg1, NN);

    // ---- fused h1 + pre-partials (MFMA) ----
    k_fused<<<NNPAD / 512, 512, 0, stream>>>(agg1, w1t, b1, cmT, partial);

    // ---- tail ----
    k_tail<<<NG, 256, 0, stream>>>(partial, W2, b2, cntg, out);
}

// Round 15
// 230.834 us; speedup vs baseline: 1.7016x; 1.7016x over previous
//
#include <hip/hip_runtime.h>

#define NN 100000
#define NNPAD 100352   // 196*512 = 256*392
#define NE 1600000
#define NG 64
#define DI 128
#define DH 256
#define DO 128
#define SEG2 25088     // cmT s-segment per block (~100 KB LDS), NNPAD = 4*SEG2
#define NPART 256
#define PSTRIDE 392    // dst range per partition (256*392 = NNPAD)
#define PCAP 7168      // partition capacity (mean 6250, sd ~79 -> 11 sigma slack)

using short8 = __attribute__((ext_vector_type(8))) short;
using f32x4  = __attribute__((ext_vector_type(4))) float;

__device__ __forceinline__ float bf2f(unsigned short u) {
    return __uint_as_float(((unsigned)u) << 16);
}
__device__ __forceinline__ unsigned short f2bf(float f) {
    unsigned u = __float_as_uint(f);
    unsigned r = (u + 0x7FFFu + ((u >> 16) & 1u)) >> 16;   // RNE
    return (unsigned short)r;
}

// ---------------- prep: x -> bf16, W1 -> w1t, partition cursor init ----------------
__global__ void k_prep(const float* __restrict__ x, unsigned short* __restrict__ xbf,
                       const float* __restrict__ W1, unsigned short* __restrict__ w1t,
                       int* __restrict__ pcur) {
    int i = blockIdx.x * blockDim.x + threadIdx.x;
    const int NX4 = NN * 32;
    if (i < NX4) {
        float4 v = ((const float4*)x)[i];
        ushort4 o;
        o.x = f2bf(v.x); o.y = f2bf(v.y); o.z = f2bf(v.z); o.w = f2bf(v.w);
        ((ushort4*)xbf)[i] = o;
    } else if (i < NX4 + DI * DH) {
        int t = i - NX4;
        int k = t / DH, n = t % DH;
        w1t[n * DI + k] = f2bf(W1[t]);
    }
    if (i < NPART) pcur[i] = i * PCAP;
}

// ---------------- radix partition of edges by dst range (256 bins) ----------------
__global__ __launch_bounds__(256) void k_partition(const int* __restrict__ src,
        const int* __restrict__ dst, int* __restrict__ pcur,
        int2* __restrict__ pe, int e) {
    __shared__ int hist[NPART];
    __shared__ int curb[NPART];
    const int EPT = 16;
    int t = threadIdx.x;
    hist[t] = 0;
    __syncthreads();
    int base = blockIdx.x * (256 * EPT) + t;
    int sA[EPT], dA[EPT];
#pragma unroll
    for (int k = 0; k < EPT; ++k) {
        int i = base + k * 256;
        if (i < e) {
            sA[k] = src[i]; dA[k] = dst[i];
            atomicAdd(&hist[dA[k] / PSTRIDE], 1);
        } else dA[k] = -1;
    }
    __syncthreads();
    curb[t] = atomicAdd(&pcur[t], hist[t]);
    __syncthreads();
#pragma unroll
    for (int k = 0; k < EPT; ++k) {
        if (dA[k] >= 0) {
            int b = dA[k] / PSTRIDE;
            int pos = atomicAdd(&curb[b], 1);   // LDS cursor, global position
            pe[pos] = make_int2(sA[k], dA[k]);
        }
    }
}

// ---------------- per-partition degree count (own partition only) ----------------
__global__ __launch_bounds__(256) void k_count(const int2* __restrict__ pe,
        const int* __restrict__ pcur, int* __restrict__ cnt) {
    __shared__ int c[PSTRIDE];
    int p = blockIdx.x;                 // 256 blocks
    int lo = p * PSTRIDE;
    int t = threadIdx.x;
    for (int i = t; i < PSTRIDE; i += 256) c[i] = 0;
    __syncthreads();
    int j1 = pcur[p];
    for (int j = p * PCAP + t; j < j1; j += 256)
        atomicAdd(&c[pe[j].y - lo], 1);
    __syncthreads();
    for (int i = t; i < PSTRIDE; i += 256) {
        int d = lo + i;
        if (d < NN) cnt[d] = c[i];
    }
}

// ---------------- exclusive scan (2-level) ----------------

__global__ void k_scan1(const int* __restrict__ in, int* __restrict__ out,
                        int* __restrict__ bsum, int n) {
    __shared__ int sh[256];
    int t = threadIdx.x;
    int i = blockIdx.x * 256 + t;
    int v = (i < n) ? in[i] : 0;
    sh[t] = v;
    __syncthreads();
    for (int off = 1; off < 256; off <<= 1) {
        int add = (t >= off) ? sh[t - off] : 0;
        __syncthreads();
        sh[t] += add;
        __syncthreads();
    }
    if (i < n) out[i] = sh[t] - v;
    if (t == 255) bsum[blockIdx.x] = sh[255];
}
__global__ void k_scan2(int* __restrict__ bsum, int* __restrict__ cntg, int nb) {
    __shared__ int sh[512];
    int t = threadIdx.x;
    if (t < NG) cntg[t] = 0;
    int v = (t < nb) ? bsum[t] : 0;
    sh[t] = v;
    __syncthreads();
    for (int off = 1; off < 512; off <<= 1) {
        int add = (t >= off) ? sh[t - off] : 0;
        __syncthreads();
        sh[t] += add;
        __syncthreads();
    }
    if (t < nb) bsum[t] = sh[t] - v;
}
// finalize rowst, dinv, gdv, per-graph counts
__global__ void k_scan3(int* __restrict__ rowst, const int* __restrict__ bsum,
                        const int* __restrict__ deg, float* __restrict__ dinv,
                        const int* __restrict__ batch, int2* __restrict__ gdv,
                        int* __restrict__ cntg, int n, int total) {
    __shared__ int sh[NG];
    int t = threadIdx.x;
    if (t < NG) sh[t] = 0;
    __syncthreads();
    int i = blockIdx.x * 256 + t;
    if (i < n) {
        float dv = rsqrtf((float)(deg[i] + 1));
        dinv[i] = dv;
        int b = batch[i];
        int2 g; g.x = __float_as_int(dv); g.y = b;
        gdv[i] = g;
        atomicAdd(&sh[b], 1);
        rowst[i] += bsum[blockIdx.x];
    }
    if (i == 0) rowst[n] = total;
    __syncthreads();
    if (t < NG && sh[t]) atomicAdd(&cntg[t], sh[t]);
}

// ---------------- place: per-partition LDS-cursor CSR fill ----------------
__global__ __launch_bounds__(256) void k_place(const int2* __restrict__ pe,
        const int* __restrict__ pcur, const int* __restrict__ rowst,
        const float* __restrict__ dinv, int2* __restrict__ csr8) {
    __shared__ int cur[PSTRIDE];
    __shared__ float dl[PSTRIDE];
    int p = blockIdx.x;                 // 256 blocks
    int lo = p * PSTRIDE;
    int t = threadIdx.x;
    for (int i = t; i < PSTRIDE; i += 256) {
        int d = lo + i;
        cur[i] = (d < NN) ? rowst[d] : 0;
        dl[i]  = (d < NN) ? dinv[d] : 0.f;
    }
    __syncthreads();
    int j1 = pcur[p];
    for (int j = p * PCAP + t; j < j1; j += 256) {
        int2 ed = pe[j];
        int a = ed.y - lo;
        float w = dinv[ed.x] * dl[a];
        int pos = atomicAdd(&cur[a], 1);
        csr8[pos] = make_int2(ed.x, __float_as_int(w));
    }
}

// ---------------- cmT build: flat streaming over per-graph contiguous (s,w) pairs ----------------
__global__ __launch_bounds__(256) void k_cmbuild(const int2* __restrict__ csr8,
        const int* __restrict__ rowst, const int* __restrict__ batch,
        const int2* __restrict__ gdv, float* __restrict__ cmT) {
    __shared__ float acc[SEG2];          // ~100 KB
    int g   = blockIdx.x >> 2;
    int seg = blockIdx.x & 3;
    int slo = seg * SEG2;
    int t = threadIdx.x;
    for (int i = t; i < SEG2; i += 256) acc[i] = 0.f;

    int lo = 0, hi = NN;
    while (lo < hi) { int m = (lo + hi) >> 1; if (batch[m] < g) lo = m + 1; else hi = m; }
    int dstart = lo;
    int lo2 = lo, hi2 = NN;
    while (lo2 < hi2) { int m = (lo2 + hi2) >> 1; if (batch[m] < g + 1) lo2 = m + 1; else hi2 = m; }
    int e0 = rowst[dstart], e1 = rowst[lo2];
    __syncthreads();

    int j = e0 + t;
    for (; j + 768 < e1; j += 1024) {
        int2 p0 = csr8[j];
        int2 p1 = csr8[j + 256];
        int2 p2 = csr8[j + 512];
        int2 p3 = csr8[j + 768];
        int a0 = p0.x - slo, a1 = p1.x - slo, a2 = p2.x - slo, a3 = p3.x - slo;
        if ((unsigned)a0 < SEG2) atomicAdd(&acc[a0], __int_as_float(p0.y));
        if ((unsigned)a1 < SEG2) atomicAdd(&acc[a1], __int_as_float(p1.y));
        if ((unsigned)a2 < SEG2) atomicAdd(&acc[a2], __int_as_float(p2.y));
        if ((unsigned)a3 < SEG2) atomicAdd(&acc[a3], __int_as_float(p3.y));
    }
    for (; j < e1; j += 256) {
        int2 p = csr8[j];
        int a = p.x - slo;
        if ((unsigned)a < SEG2) atomicAdd(&acc[a], __int_as_float(p.y));
    }
    __syncthreads();

    float* row = cmT + (size_t)g * NNPAD;
    for (int i = t; i < SEG2; i += 256) {
        int s = slo + i;
        float v = acc[i];
        if (s < NN) {
            int2 gv = gdv[s];
            if (gv.y == g) { float dv = __int_as_float(gv.x); v += dv * dv; }
        }
        row[s] = v;
    }
}

// ---------------- layer-1 aggregation: weights streamed from packed CSR ----------------
__global__ __launch_bounds__(256) void k_agg16(const unsigned short* __restrict__ feat,
        const int2* __restrict__ csr8, const int* __restrict__ row_start,
        const float* __restrict__ dinv, unsigned short* __restrict__ out, int n) {
    int gid = blockIdx.x * blockDim.x + threadIdx.x;
    int node = gid >> 4;
    int lane = threadIdx.x & 15;
    if (node >= n) return;
    const short8* f8 = (const short8*)feat;
    float wd = dinv[node];
    float wd2 = wd * wd;
    short8 a = f8[(size_t)node * 16 + lane];
    float acc[8];
#pragma unroll
    for (int i = 0; i < 8; ++i) acc[i] = bf2f((unsigned short)a[i]) * wd2;
    int j = row_start[node], end = row_start[node + 1];
    for (; j + 3 < end; j += 4) {
        int2 p0 = csr8[j], p1 = csr8[j + 1], p2 = csr8[j + 2], p3 = csr8[j + 3];
        float w0 = __int_as_float(p0.y), w1 = __int_as_float(p1.y);
        float w2 = __int_as_float(p2.y), w3 = __int_as_float(p3.y);
        short8 v0 = f8[(size_t)p0.x * 16 + lane];
        short8 v1 = f8[(size_t)p1.x * 16 + lane];
        short8 v2 = f8[(size_t)p2.x * 16 + lane];
        short8 v3 = f8[(size_t)p3.x * 16 + lane];
#pragma unroll
        for (int i = 0; i < 8; ++i)
            acc[i] += w0 * bf2f((unsigned short)v0[i]) + w1 * bf2f((unsigned short)v1[i])
                    + w2 * bf2f((unsigned short)v2[i]) + w3 * bf2f((unsigned short)v3[i]);
    }
    for (; j < end; ++j) {
        int2 p = csr8[j];
        float w = __int_as_float(p.y);
        short8 v = f8[(size_t)p.x * 16 + lane];
#pragma unroll
        for (int i = 0; i < 8; ++i) acc[i] += w * bf2f((unsigned short)v[i]);
    }
    short8 o;
#pragma unroll
    for (int i = 0; i < 8; ++i) o[i] = (short)f2bf(acc[i]);
    ((short8*)out)[(size_t)node * 16 + lane] = o;
}

// ---------------- fused: h1-chunk MFMA (LDS) + pre-partial MFMA ----------------
__global__ __launch_bounds__(512) void k_fused(const unsigned short* __restrict__ agg1,
        const unsigned short* __restrict__ w1t, const float* __restrict__ b1,
        const float* __restrict__ cmT, float* __restrict__ partial) {
    __shared__ unsigned short Ws[256 * 128];  // 64 KB
    __shared__ unsigned short As[64 * 128];   // 16 KB
    __shared__ unsigned short Hs[256 * 64];   // 32 KB
    __shared__ unsigned short Cs[64 * 64];    // 8 KB

    const int tid = threadIdx.x;
    const int sb = blockIdx.x * 512;

#pragma unroll
    for (int i = 0; i < 8; ++i) {
        int c = tid + i * 512;
        int row = c >> 4, seg = c & 15;
        uint4 v = *(const uint4*)(w1t + row * 128 + seg * 8);
        *(uint4*)((char*)Ws + row * 256 + ((seg * 16) ^ ((row & 7) << 4))) = v;
    }

    const int w  = tid >> 6;
    const int l  = tid & 63;
    const int lr = l & 15;
    const int lg = l >> 4;
    const int swz = (lr & 7) << 4;
    const int j0 = w * 32;

    float bb0 = b1[j0 + lr];
    float bb1 = b1[j0 + 16 + lr];

    f32x4 acc2[4][2] = {};

    for (int c = 0; c < 8; ++c) {
        int s0 = sb + c * 64;
        __syncthreads();
#pragma unroll
        for (int i = 0; i < 2; ++i) {
            int cc = tid + i * 512;
            int row = cc >> 4, seg = cc & 15;
            uint4 v = make_uint4(0, 0, 0, 0);
            int node = s0 + row;
            if (node < NN) v = *(const uint4*)(agg1 + (size_t)node * 128 + seg * 8);
            *(uint4*)((char*)As + row * 256 + ((seg * 16) ^ ((row & 7) << 4))) = v;
        }
        {
            int g = tid >> 3, seg = tid & 7;
            const float* cp = cmT + (size_t)g * NNPAD + s0 + seg * 8;
            float4 f0 = *(const float4*)cp;
            float4 f1 = *(const float4*)(cp + 4);
            uint4 v;
            v.x = (unsigned)f2bf(f0.x) | ((unsigned)f2bf(f0.y) << 16);
            v.y = (unsigned)f2bf(f0.z) | ((unsigned)f2bf(f0.w) << 16);
            v.z = (unsigned)f2bf(f1.x) | ((unsigned)f2bf(f1.y) << 16);
            v.w = (unsigned)f2bf(f1.z) | ((unsigned)f2bf(f1.w) << 16);
            *(uint4*)((char*)Cs + g * 128 + ((seg * 16) ^ ((g & 7) << 4))) = v;
        }
        __syncthreads();

        // phase A: h1 chunk = relu(agg1c @ w1t^T + b1), K=128
        f32x4 accA[4][2] = {};
#pragma unroll
        for (int ks = 0; ks < 4; ++ks) {
            int kb = ks * 64 + lg * 16;
            short8 a[4];
#pragma unroll
            for (int m = 0; m < 4; ++m)
                a[m] = *(const short8*)((const char*)As + (m * 16 + lr) * 256 + (kb ^ swz));
#pragma unroll
            for (int n = 0; n < 2; ++n) {
                short8 b = *(const short8*)((const char*)Ws + (j0 + n * 16 + lr) * 256 + (kb ^ swz));
#pragma unroll
                for (int m = 0; m < 4; ++m)
                    accA[m][n] = __builtin_amdgcn_mfma_f32_16x16x32_bf16(a[m], b, accA[m][n], 0, 0, 0);
            }
        }
#pragma unroll
        for (int n = 0; n < 2; ++n) {
            int j = j0 + n * 16 + lr;
            float bbv = n ? bb1 : bb0;
#pragma unroll
            for (int m = 0; m < 4; ++m) {
                float v0 = fmaxf(accA[m][n][0] + bbv, 0.f);
                float v1 = fmaxf(accA[m][n][1] + bbv, 0.f);
                float v2 = fmaxf(accA[m][n][2] + bbv, 0.f);
                float v3 = fmaxf(accA[m][n][3] + bbv, 0.f);
                uint2 p;
                p.x = (unsigned)f2bf(v0) | ((unsigned)f2bf(v1) << 16);
                p.y = (unsigned)f2bf(v2) | ((unsigned)f2bf(v3) << 16);
                *(uint2*)((char*)Hs + j * 128 + (((m * 16 + lg * 4) * 2) ^ swz)) = p;
            }
        }
        __syncthreads();

        // phase B: acc2[g][j] += Cs @ Hs^T, K=64
#pragma unroll
        for (int ks = 0; ks < 2; ++ks) {
            int kb = ks * 64 + lg * 16;
            short8 a[4];
#pragma unroll
            for (int mg = 0; mg < 4; ++mg)
                a[mg] = *(const short8*)((const char*)Cs + (mg * 16 + lr) * 128 + (kb ^ swz));
#pragma unroll
            for (int n = 0; n < 2; ++n) {
                short8 b = *(const short8*)((const char*)Hs + (j0 + n * 16 + lr) * 128 + (kb ^ swz));
#pragma unroll
                for (int mg = 0; mg < 4; ++mg)
                    acc2[mg][n] = __builtin_amdgcn_mfma_f32_16x16x32_bf16(a[mg], b, acc2[mg][n], 0, 0, 0);
            }
        }
    }

    float* pb = partial + (size_t)blockIdx.x * (NG * DH);
#pragma unroll
    for (int mg = 0; mg < 4; ++mg)
#pragma unroll
        for (int n = 0; n < 2; ++n)
#pragma unroll
            for (int r = 0; r < 4; ++r) {
                int g = mg * 16 + lg * 4 + r;
                int j = j0 + n * 16 + lr;
                pb[g * DH + j] = acc2[mg][n][r];
            }
}

// ---------------- tail: reduce 196 partials + final 64x256x128 GEMM ----------------
__global__ __launch_bounds__(256) void k_tail(const float* __restrict__ partial,
        const float* __restrict__ W2, const float* __restrict__ b2,
        const int* __restrict__ cntg, float* __restrict__ out) {
    __shared__ float pre[DH];
    int g = blockIdx.x;
    int t = threadIdx.x;
    float s0 = 0.f, s1 = 0.f, s2 = 0.f, s3 = 0.f;
    for (int b = 0; b < 196; b += 4) {
        s0 += partial[(size_t)b * (NG * DH) + g * DH + t];
        s1 += partial[(size_t)(b + 1) * (NG * DH) + g * DH + t];
        s2 += partial[(size_t)(b + 2) * (NG * DH) + g * DH + t];
        s3 += partial[(size_t)(b + 3) * (NG * DH) + g * DH + t];
    }
    pre[t] = (s0 + s1) + (s2 + s3);
    __syncthreads();
    if (t < DO) {
        float acc = (float)cntg[g] * b2[t];
        for (int k = 0; k < DH; ++k)
            acc = fmaf(pre[k], W2[k * DO + t], acc);
        out[g * DO + t] = acc;
    }
}

// ---------------- launch ----------------

extern "C" void kernel_launch(void* const* d_in, const int* in_sizes, int n_in,
                              void* d_out, int out_size, void* d_ws, size_t ws_size,
                              hipStream_t stream) {
    const float* x     = (const float*)d_in[0];
    const int*   ei    = (const int*)d_in[1];
    const int*   batch = (const int*)d_in[2];
    const float* W1    = (const float*)d_in[3];
    const float* b1    = (const float*)d_in[4];
    const float* W2    = (const float*)d_in[5];
    const float* b2    = (const float*)d_in[6];
    float* out = (float*)d_out;

    const int* src = ei;
    const int* dst = ei + NE;

    // workspace layout, peak ~120 MB
    char* ws = (char*)d_ws;
    float*          dinv    = (float*)(ws + 0);                  // 400 KB
    int*            cnt_in  = (int*)(ws + 524288);               // degree counts
    int*            rowst   = (int*)(ws + 1048576);              // NN+1
    int*            bsum    = (int*)(ws + 1572864);
    int*            cntg    = (int*)(ws + 1576960);
    unsigned short* w1t     = (unsigned short*)(ws + 1577216);   // 64 KB
    int2*           gdv     = (int2*)(ws + 1642752);             // 800 KB
    int2*           csr8    = (int2*)(ws + 2443264);             // 12.8 MB
    unsigned short* xbf     = (unsigned short*)(ws + 15243264);  // 25.6 MB
    unsigned short* agg1    = (unsigned short*)(ws + 40843264);  // 25.6 MB
    float*          cmT     = (float*)(ws + 66443264);           // 25.69 MB
    float*          partial = (float*)(ws + 92133376);           // 12.85 MB
    int2*           pe      = (int2*)(ws + 104978432);           // 14.68 MB
    int*            pcur    = (int*)(ws + 119658496);            // 1 KB

    const int BLK = 256;
    auto cdiv = [](int a, int b) { return (a + b - 1) / b; };
    const int NB = cdiv(NN, 256);   // 391

    // ---- prep (cvt + wt + pcur init) ----
    k_prep<<<cdiv(NN * 32 + DI * DH, BLK), BLK, 0, stream>>>(x, xbf, W1, w1t, pcur);

    // ---- radix partition edges by dst range (256 bins) ----
    k_partition<<<cdiv(NE, 256 * 16), 256, 0, stream>>>(src, dst, pcur, pe, NE);

    // ---- per-partition degree count ----
    k_count<<<NPART, 256, 0, stream>>>(pe, pcur, cnt_in);

    // ---- scan (+ dinv/gdv/graph-counts) ----
    k_scan1<<<NB, 256, 0, stream>>>(cnt_in, rowst, bsum, NN);
    k_scan2<<<1, 512, 0, stream>>>(bsum, cntg, NB);
    k_scan3<<<NB, 256, 0, stream>>>(rowst, bsum, cnt_in, dinv, batch, gdv, cntg, NN, NE);

    // ---- place: per-partition CSR fill via LDS cursors ----
    k_place<<<NPART, 256, 0, stream>>>(pe, pcur, rowst, dinv, csr8);

    // ---- cmT from packed CSR (flat streaming, LDS-accumulated) ----
    k_cmbuild<<<NG * 4, 256, 0, stream>>>(csr8, rowst, batch, gdv, cmT);

    // ---- layer 1 aggregation ----
    k_agg16<<<cdiv(NN * 16, BLK), BLK, 0, stream>>>(xbf, csr8, rowst, dinv, agg1, NN);

    // ---- fused h1 + pre-partials (MFMA) ----
    k_fused<<<NNPAD / 512, 512, 0, stream>>>(agg1, w1t, b1, cmT, partial);

    // ---- tail ----
    k_tail<<<NG, 256, 0, stream>>>(partial, W2, b2, cntg, out);
}

// Round 16
// 229.342 us; speedup vs baseline: 1.7127x; 1.0065x over previous
//
#include <hip/hip_runtime.h>

#define NN 100000
#define NNPAD 100352   // 196*512 = 256*392
#define NE 1600000
#define NG 64
#define DI 128
#define DH 256
#define DO 128
#define SEG2 25088     // cmT s-segment per block (~100 KB LDS), NNPAD = 4*SEG2
#define NPART 256
#define PSTRIDE 392    // dst range per partition (256*392 = NNPAD)
#define PCAP 7168      // partition capacity (mean 6250, sd ~79 -> 11 sigma slack)
#define PB 391         // partition blocks: 391*4096 >= NE

using short8 = __attribute__((ext_vector_type(8))) short;
using f32x4  = __attribute__((ext_vector_type(4))) float;

__device__ __forceinline__ float bf2f(unsigned short u) {
    return __uint_as_float(((unsigned)u) << 16);
}
__device__ __forceinline__ unsigned short f2bf(float f) {
    unsigned u = __float_as_uint(f);
    unsigned r = (u + 0x7FFFu + ((u >> 16) & 1u)) >> 16;   // RNE
    return (unsigned short)r;
}

// ---------------- prep + radix partition, merged (independent work) ----------------
// blocks [0, PB): partition edges into 256 dst-range bins (pcur holds RELATIVE offsets, pre-zeroed)
// blocks [PB, ..): x -> bf16, W1 -> w1t
__global__ __launch_bounds__(256) void k_prep(const float* __restrict__ x,
        unsigned short* __restrict__ xbf, const float* __restrict__ W1,
        unsigned short* __restrict__ w1t, const int* __restrict__ src,
        const int* __restrict__ dst, int* __restrict__ pcur, int2* __restrict__ pe) {
    int t = threadIdx.x;
    if (blockIdx.x < PB) {
        __shared__ int hist[NPART];
        __shared__ int curb[NPART];
        const int EPT = 16;
        hist[t] = 0;
        __syncthreads();
        int base = blockIdx.x * (256 * EPT) + t;
        int sA[EPT], dA[EPT];
#pragma unroll
        for (int k = 0; k < EPT; ++k) {
            int i = base + k * 256;
            if (i < NE) {
                sA[k] = src[i]; dA[k] = dst[i];
                atomicAdd(&hist[dA[k] / PSTRIDE], 1);
            } else dA[k] = -1;
        }
        __syncthreads();
        curb[t] = t * PCAP + atomicAdd(&pcur[t], hist[t]);
        __syncthreads();
#pragma unroll
        for (int k = 0; k < EPT; ++k) {
            if (dA[k] >= 0) {
                int b = dA[k] / PSTRIDE;
                int pos = atomicAdd(&curb[b], 1);
                pe[pos] = make_int2(sA[k], dA[k]);
            }
        }
        return;
    }
    int i = (blockIdx.x - PB) * 256 + t;
    const int NX4 = NN * 32;
    if (i < NX4) {
        float4 v = ((const float4*)x)[i];
        ushort4 o;
        o.x = f2bf(v.x); o.y = f2bf(v.y); o.z = f2bf(v.z); o.w = f2bf(v.w);
        ((ushort4*)xbf)[i] = o;
    } else if (i < NX4 + DI * DH) {
        int tt = i - NX4;
        int k = tt / DH, n = tt % DH;
        w1t[n * DI + k] = f2bf(W1[tt]);
    }
}

// ---------------- count + partition-local exclusive scan ----------------
// writes cnt[d] (degree), rowst[d] (partition-local exclusive prefix), pt[p] (partition total)
__global__ __launch_bounds__(256) void k_count(const int2* __restrict__ pe,
        const int* __restrict__ pcur, int* __restrict__ cnt,
        int* __restrict__ rowst, int* __restrict__ pt) {
    __shared__ int c[512];
    int p = blockIdx.x;                 // 256 blocks
    int lo = p * PSTRIDE;
    int t = threadIdx.x;
    c[t] = 0; c[t + 256] = 0;
    __syncthreads();
    int j1 = p * PCAP + pcur[p];
    for (int j = p * PCAP + t; j < j1; j += 256)
        atomicAdd(&c[pe[j].y - lo], 1);
    __syncthreads();
    int cc0 = c[t], cc1 = c[t + 256];
    // inclusive Hillis-Steele over 512 (256 threads x 2 elems)
    for (int off = 1; off < 512; off <<= 1) {
        int v0 = (t >= off) ? c[t - off] : 0;
        int v1 = (t + 256 >= off) ? c[t + 256 - off] : 0;
        __syncthreads();
        c[t] += v0; c[t + 256] += v1;
        __syncthreads();
    }
    if (t < PSTRIDE) {
        int d = lo + t;
        if (d < NN) { cnt[d] = cc0; rowst[d] = c[t] - cc0; }
    }
    if (t + 256 < PSTRIDE) {
        int d = lo + t + 256;
        if (d < NN) { cnt[d] = cc1; rowst[d] = c[t + 256] - cc1; }
    }
    if (t == 0) pt[p] = c[511];
}

// exclusive scan over 256 partition totals (+ cntg zero)
__global__ void k_scan2p(int* __restrict__ pt, int* __restrict__ cntg) {
    __shared__ int sh[256];
    int t = threadIdx.x;
    if (t < NG) cntg[t] = 0;
    int v = pt[t];
    sh[t] = v;
    __syncthreads();
    for (int off = 1; off < 256; off <<= 1) {
        int add = (t >= off) ? sh[t - off] : 0;
        __syncthreads();
        sh[t] += add;
        __syncthreads();
    }
    pt[t] = sh[t] - v;
}

// finalize rowst (+ partition offsets), dinv, gdv, per-graph counts
__global__ void k_scan3(int* __restrict__ rowst, const int* __restrict__ pt,
                        const int* __restrict__ deg, float* __restrict__ dinv,
                        const int* __restrict__ batch, int2* __restrict__ gdv,
                        int* __restrict__ cntg, int n, int total) {
    __shared__ int sh[NG];
    int t = threadIdx.x;
    if (t < NG) sh[t] = 0;
    __syncthreads();
    int i = blockIdx.x * 256 + t;
    if (i < n) {
        float dv = rsqrtf((float)(deg[i] + 1));
        dinv[i] = dv;
        int b = batch[i];
        int2 g; g.x = __float_as_int(dv); g.y = b;
        gdv[i] = g;
        atomicAdd(&sh[b], 1);
        rowst[i] += pt[i / PSTRIDE];
    }
    if (i == 0) rowst[n] = total;
    __syncthreads();
    if (t < NG && sh[t]) atomicAdd(&cntg[t], sh[t]);
}

// ---------------- place: per-partition LDS-cursor CSR fill ----------------
__global__ __launch_bounds__(256) void k_place(const int2* __restrict__ pe,
        const int* __restrict__ pcur, const int* __restrict__ rowst,
        const float* __restrict__ dinv, int2* __restrict__ csr8) {
    __shared__ int cur[PSTRIDE];
    __shared__ float dl[PSTRIDE];
    int p = blockIdx.x;                 // 256 blocks
    int lo = p * PSTRIDE;
    int t = threadIdx.x;
    for (int i = t; i < PSTRIDE; i += 256) {
        int d = lo + i;
        cur[i] = (d < NN) ? rowst[d] : 0;
        dl[i]  = (d < NN) ? dinv[d] : 0.f;
    }
    __syncthreads();
    int j1 = p * PCAP + pcur[p];
    for (int j = p * PCAP + t; j < j1; j += 256) {
        int2 ed = pe[j];
        int a = ed.y - lo;
        float w = dinv[ed.x] * dl[a];
        int pos = atomicAdd(&cur[a], 1);
        csr8[pos] = make_int2(ed.x, __float_as_int(w));
    }
}

// ---------------- cmT build: flat streaming over per-graph contiguous (s,w) pairs ----------------
__global__ __launch_bounds__(256) void k_cmbuild(const int2* __restrict__ csr8,
        const int* __restrict__ rowst, const int* __restrict__ batch,
        const int2* __restrict__ gdv, float* __restrict__ cmT) {
    __shared__ float acc[SEG2];          // ~100 KB
    int g   = blockIdx.x >> 2;
    int seg = blockIdx.x & 3;
    int slo = seg * SEG2;
    int t = threadIdx.x;
    for (int i = t; i < SEG2; i += 256) acc[i] = 0.f;

    int lo = 0, hi = NN;
    while (lo < hi) { int m = (lo + hi) >> 1; if (batch[m] < g) lo = m + 1; else hi = m; }
    int dstart = lo;
    int lo2 = lo, hi2 = NN;
    while (lo2 < hi2) { int m = (lo2 + hi2) >> 1; if (batch[m] < g + 1) lo2 = m + 1; else hi2 = m; }
    int e0 = rowst[dstart], e1 = rowst[lo2];
    __syncthreads();

    int j = e0 + t;
    for (; j + 768 < e1; j += 1024) {
        int2 p0 = csr8[j];
        int2 p1 = csr8[j + 256];
        int2 p2 = csr8[j + 512];
        int2 p3 = csr8[j + 768];
        int a0 = p0.x - slo, a1 = p1.x - slo, a2 = p2.x - slo, a3 = p3.x - slo;
        if ((unsigned)a0 < SEG2) atomicAdd(&acc[a0], __int_as_float(p0.y));
        if ((unsigned)a1 < SEG2) atomicAdd(&acc[a1], __int_as_float(p1.y));
        if ((unsigned)a2 < SEG2) atomicAdd(&acc[a2], __int_as_float(p2.y));
        if ((unsigned)a3 < SEG2) atomicAdd(&acc[a3], __int_as_float(p3.y));
    }
    for (; j < e1; j += 256) {
        int2 p = csr8[j];
        int a = p.x - slo;
        if ((unsigned)a < SEG2) atomicAdd(&acc[a], __int_as_float(p.y));
    }
    __syncthreads();

    float* row = cmT + (size_t)g * NNPAD;
    for (int i = t; i < SEG2; i += 256) {
        int s = slo + i;
        float v = acc[i];
        if (s < NN) {
            int2 gv = gdv[s];
            if (gv.y == g) { float dv = __int_as_float(gv.x); v += dv * dv; }
        }
        row[s] = v;
    }
}

// ---------------- layer-1 aggregation: weights streamed from packed CSR, 8-way unroll ----------------
__global__ __launch_bounds__(256) void k_agg16(const unsigned short* __restrict__ feat,
        const int2* __restrict__ csr8, const int* __restrict__ row_start,
        const float* __restrict__ dinv, unsigned short* __restrict__ out, int n) {
    int gid = blockIdx.x * blockDim.x + threadIdx.x;
    int node = gid >> 4;
    int lane = threadIdx.x & 15;
    if (node >= n) return;
    const short8* f8 = (const short8*)feat;
    float wd = dinv[node];
    float wd2 = wd * wd;
    short8 a = f8[(size_t)node * 16 + lane];
    float acc[8];
#pragma unroll
    for (int i = 0; i < 8; ++i) acc[i] = bf2f((unsigned short)a[i]) * wd2;
    int j = row_start[node], end = row_start[node + 1];
    for (; j + 7 < end; j += 8) {
        int2 p0 = csr8[j],     p1 = csr8[j + 1], p2 = csr8[j + 2], p3 = csr8[j + 3];
        int2 p4 = csr8[j + 4], p5 = csr8[j + 5], p6 = csr8[j + 6], p7 = csr8[j + 7];
        short8 v0 = f8[(size_t)p0.x * 16 + lane];
        short8 v1 = f8[(size_t)p1.x * 16 + lane];
        short8 v2 = f8[(size_t)p2.x * 16 + lane];
        short8 v3 = f8[(size_t)p3.x * 16 + lane];
        short8 v4 = f8[(size_t)p4.x * 16 + lane];
        short8 v5 = f8[(size_t)p5.x * 16 + lane];
        short8 v6 = f8[(size_t)p6.x * 16 + lane];
        short8 v7 = f8[(size_t)p7.x * 16 + lane];
        float w0 = __int_as_float(p0.y), w1 = __int_as_float(p1.y);
        float w2 = __int_as_float(p2.y), w3 = __int_as_float(p3.y);
        float w4 = __int_as_float(p4.y), w5 = __int_as_float(p5.y);
        float w6 = __int_as_float(p6.y), w7 = __int_as_float(p7.y);
#pragma unroll
        for (int i = 0; i < 8; ++i)
            acc[i] += w0 * bf2f((unsigned short)v0[i]) + w1 * bf2f((unsigned short)v1[i])
                    + w2 * bf2f((unsigned short)v2[i]) + w3 * bf2f((unsigned short)v3[i])
                    + w4 * bf2f((unsigned short)v4[i]) + w5 * bf2f((unsigned short)v5[i])
                    + w6 * bf2f((unsigned short)v6[i]) + w7 * bf2f((unsigned short)v7[i]);
    }
    for (; j + 3 < end; j += 4) {
        int2 p0 = csr8[j], p1 = csr8[j + 1], p2 = csr8[j + 2], p3 = csr8[j + 3];
        float w0 = __int_as_float(p0.y), w1 = __int_as_float(p1.y);
        float w2 = __int_as_float(p2.y), w3 = __int_as_float(p3.y);
        short8 v0 = f8[(size_t)p0.x * 16 + lane];
        short8 v1 = f8[(size_t)p1.x * 16 + lane];
        short8 v2 = f8[(size_t)p2.x * 16 + lane];
        short8 v3 = f8[(size_t)p3.x * 16 + lane];
#pragma unroll
        for (int i = 0; i < 8; ++i)
            acc[i] += w0 * bf2f((unsigned short)v0[i]) + w1 * bf2f((unsigned short)v1[i])
                    + w2 * bf2f((unsigned short)v2[i]) + w3 * bf2f((unsigned short)v3[i]);
    }
    for (; j < end; ++j) {
        int2 p = csr8[j];
        float w = __int_as_float(p.y);
        short8 v = f8[(size_t)p.x * 16 + lane];
#pragma unroll
        for (int i = 0; i < 8; ++i) acc[i] += w * bf2f((unsigned short)v[i]);
    }
    short8 o;
#pragma unroll
    for (int i = 0; i < 8; ++i) o[i] = (short)f2bf(acc[i]);
    ((short8*)out)[(size_t)node * 16 + lane] = o;
}

// ---------------- fused: h1-chunk MFMA (LDS) + pre-partial MFMA ----------------
__global__ __launch_bounds__(512) void k_fused(const unsigned short* __restrict__ agg1,
        const unsigned short* __restrict__ w1t, const float* __restrict__ b1,
        const float* __restrict__ cmT, float* __restrict__ partial) {
    __shared__ unsigned short Ws[256 * 128];  // 64 KB
    __shared__ unsigned short As[64 * 128];   // 16 KB
    __shared__ unsigned short Hs[256 * 64];   // 32 KB
    __shared__ unsigned short Cs[64 * 64];    // 8 KB

    const int tid = threadIdx.x;
    const int sb = blockIdx.x * 512;

#pragma unroll
    for (int i = 0; i < 8; ++i) {
        int c = tid + i * 512;
        int row = c >> 4, seg = c & 15;
        uint4 v = *(const uint4*)(w1t + row * 128 + seg * 8);
        *(uint4*)((char*)Ws + row * 256 + ((seg * 16) ^ ((row & 7) << 4))) = v;
    }

    const int w  = tid >> 6;
    const int l  = tid & 63;
    const int lr = l & 15;
    const int lg = l >> 4;
    const int swz = (lr & 7) << 4;
    const int j0 = w * 32;

    float bb0 = b1[j0 + lr];
    float bb1 = b1[j0 + 16 + lr];

    f32x4 acc2[4][2] = {};

    for (int c = 0; c < 8; ++c) {
        int s0 = sb + c * 64;
        __syncthreads();
#pragma unroll
        for (int i = 0; i < 2; ++i) {
            int cc = tid + i * 512;
            int row = cc >> 4, seg = cc & 15;
            uint4 v = make_uint4(0, 0, 0, 0);
            int node = s0 + row;
            if (node < NN) v = *(const uint4*)(agg1 + (size_t)node * 128 + seg * 8);
            *(uint4*)((char*)As + row * 256 + ((seg * 16) ^ ((row & 7) << 4))) = v;
        }
        {
            int g = tid >> 3, seg = tid & 7;
            const float* cp = cmT + (size_t)g * NNPAD + s0 + seg * 8;
            float4 f0 = *(const float4*)cp;
            float4 f1 = *(const float4*)(cp + 4);
            uint4 v;
            v.x = (unsigned)f2bf(f0.x) | ((unsigned)f2bf(f0.y) << 16);
            v.y = (unsigned)f2bf(f0.z) | ((unsigned)f2bf(f0.w) << 16);
            v.z = (unsigned)f2bf(f1.x) | ((unsigned)f2bf(f1.y) << 16);
            v.w = (unsigned)f2bf(f1.z) | ((unsigned)f2bf(f1.w) << 16);
            *(uint4*)((char*)Cs + g * 128 + ((seg * 16) ^ ((g & 7) << 4))) = v;
        }
        __syncthreads();

        // phase A: h1 chunk = relu(agg1c @ w1t^T + b1), K=128
        f32x4 accA[4][2] = {};
#pragma unroll
        for (int ks = 0; ks < 4; ++ks) {
            int kb = ks * 64 + lg * 16;
            short8 a[4];
#pragma unroll
            for (int m = 0; m < 4; ++m)
                a[m] = *(const short8*)((const char*)As + (m * 16 + lr) * 256 + (kb ^ swz));
#pragma unroll
            for (int n = 0; n < 2; ++n) {
                short8 b = *(const short8*)((const char*)Ws + (j0 + n * 16 + lr) * 256 + (kb ^ swz));
#pragma unroll
                for (int m = 0; m < 4; ++m)
                    accA[m][n] = __builtin_amdgcn_mfma_f32_16x16x32_bf16(a[m], b, accA[m][n], 0, 0, 0);
            }
        }
#pragma unroll
        for (int n = 0; n < 2; ++n) {
            int j = j0 + n * 16 + lr;
            float bbv = n ? bb1 : bb0;
#pragma unroll
            for (int m = 0; m < 4; ++m) {
                float v0 = fmaxf(accA[m][n][0] + bbv, 0.f);
                float v1 = fmaxf(accA[m][n][1] + bbv, 0.f);
                float v2 = fmaxf(accA[m][n][2] + bbv, 0.f);
                float v3 = fmaxf(accA[m][n][3] + bbv, 0.f);
                uint2 p;
                p.x = (unsigned)f2bf(v0) | ((unsigned)f2bf(v1) << 16);
                p.y = (unsigned)f2bf(v2) | ((unsigned)f2bf(v3) << 16);
                *(uint2*)((char*)Hs + j * 128 + (((m * 16 + lg * 4) * 2) ^ swz)) = p;
            }
        }
        __syncthreads();

        // phase B: acc2[g][j] += Cs @ Hs^T, K=64
#pragma unroll
        for (int ks = 0; ks < 2; ++ks) {
            int kb = ks * 64 + lg * 16;
            short8 a[4];
#pragma unroll
            for (int mg = 0; mg < 4; ++mg)
                a[mg] = *(const short8*)((const char*)Cs + (mg * 16 + lr) * 128 + (kb ^ swz));
#pragma unroll
            for (int n = 0; n < 2; ++n) {
                short8 b = *(const short8*)((const char*)Hs + (j0 + n * 16 + lr) * 128 + (kb ^ swz));
#pragma unroll
                for (int mg = 0; mg < 4; ++mg)
                    acc2[mg][n] = __builtin_amdgcn_mfma_f32_16x16x32_bf16(a[mg], b, acc2[mg][n], 0, 0, 0);
            }
        }
    }

    float* pb = partial + (size_t)blockIdx.x * (NG * DH);
#pragma unroll
    for (int mg = 0; mg < 4; ++mg)
#pragma unroll
        for (int n = 0; n < 2; ++n)
#pragma unroll
            for (int r = 0; r < 4; ++r) {
                int g = mg * 16 + lg * 4 + r;
                int j = j0 + n * 16 + lr;
                pb[g * DH + j] = acc2[mg][n][r];
            }
}

// ---------------- tail: reduce 196 partials + final 64x256x128 GEMM ----------------
__global__ __launch_bounds__(256) void k_tail(const float* __restrict__ partial,
        const float* __restrict__ W2, const float* __restrict__ b2,
        const int* __restrict__ cntg, float* __restrict__ out) {
    __shared__ float pre[DH];
    int g = blockIdx.x;
    int t = threadIdx.x;
    float s0 = 0.f, s1 = 0.f, s2 = 0.f, s3 = 0.f;
    for (int b = 0; b < 196; b += 4) {
        s0 += partial[(size_t)b * (NG * DH) + g * DH + t];
        s1 += partial[(size_t)(b + 1) * (NG * DH) + g * DH + t];
        s2 += partial[(size_t)(b + 2) * (NG * DH) + g * DH + t];
        s3 += partial[(size_t)(b + 3) * (NG * DH) + g * DH + t];
    }
    pre[t] = (s0 + s1) + (s2 + s3);
    __syncthreads();
    if (t < DO) {
        float acc = (float)cntg[g] * b2[t];
        for (int k = 0; k < DH; ++k)
            acc = fmaf(pre[k], W2[k * DO + t], acc);
        out[g * DO + t] = acc;
    }
}

// ---------------- launch ----------------

extern "C" void kernel_launch(void* const* d_in, const int* in_sizes, int n_in,
                              void* d_out, int out_size, void* d_ws, size_t ws_size,
                              hipStream_t stream) {
    const float* x     = (const float*)d_in[0];
    const int*   ei    = (const int*)d_in[1];
    const int*   batch = (const int*)d_in[2];
    const float* W1    = (const float*)d_in[3];
    const float* b1    = (const float*)d_in[4];
    const float* W2    = (const float*)d_in[5];
    const float* b2    = (const float*)d_in[6];
    float* out = (float*)d_out;

    const int* src = ei;
    const int* dst = ei + NE;

    // workspace layout, peak ~120 MB
    char* ws = (char*)d_ws;
    float*          dinv    = (float*)(ws + 0);                  // 400 KB
    int*            cnt_in  = (int*)(ws + 524288);               // degree counts
    int*            rowst   = (int*)(ws + 1048576);              // NN+1
    int*            pt      = (int*)(ws + 1572864);              // 1 KB partition totals
    int*            cntg    = (int*)(ws + 1576960);
    unsigned short* w1t     = (unsigned short*)(ws + 1577216);   // 64 KB
    int2*           gdv     = (int2*)(ws + 1642752);             // 800 KB
    int2*           csr8    = (int2*)(ws + 2443264);             // 12.8 MB
    unsigned short* xbf     = (unsigned short*)(ws + 15243264);  // 25.6 MB
    unsigned short* agg1    = (unsigned short*)(ws + 40843264);  // 25.6 MB
    float*          cmT     = (float*)(ws + 66443264);           // 25.69 MB
    float*          partial = (float*)(ws + 92133376);           // 12.85 MB
    int2*           pe      = (int2*)(ws + 104978432);           // 14.68 MB
    int*            pcur    = (int*)(ws + 119658496);            // 1 KB

    const int BLK = 256;
    auto cdiv = [](int a, int b) { return (a + b - 1) / b; };
    const int NB = cdiv(NN, 256);   // 391

    // ---- zero relative partition cursors ----
    hipMemsetAsync(pcur, 0, NPART * 4, stream);

    // ---- prep (cvt + wt) merged with radix partition ----
    {
        int prep_blocks = cdiv(NN * 32 + DI * DH, BLK);
        k_prep<<<PB + prep_blocks, BLK, 0, stream>>>(x, xbf, W1, w1t, src, dst, pcur, pe);
    }

    // ---- per-partition degree count + local prefix ----
    k_count<<<NPART, 256, 0, stream>>>(pe, pcur, cnt_in, rowst, pt);

    // ---- scan partition totals; finalize rowst/dinv/gdv/graph counts ----
    k_scan2p<<<1, 256, 0, stream>>>(pt, cntg);
    k_scan3<<<NB, 256, 0, stream>>>(rowst, pt, cnt_in, dinv, batch, gdv, cntg, NN, NE);

    // ---- place: per-partition CSR fill via LDS cursors ----
    k_place<<<NPART, 256, 0, stream>>>(pe, pcur, rowst, dinv, csr8);

    // ---- cmT from packed CSR (flat streaming, LDS-accumulated) ----
    k_cmbuild<<<NG * 4, 256, 0, stream>>>(csr8, rowst, batch, gdv, cmT);

    // ---- layer 1 aggregation ----
    k_agg16<<<cdiv(NN * 16, BLK), BLK, 0, stream>>>(xbf, csr8, rowst, dinv, agg1, NN);

    // ---- fused h1 + pre-partials (MFMA) ----
    k_fused<<<NNPAD / 512, 512, 0, stream>>>(agg1, w1t, b1, cmT, partial);

    // ---- tail ----
    k_tail<<<NG, 256, 0, stream>>>(partial, W2, b2, cntg, out);
}

// Round 17
// 223.156 us; speedup vs baseline: 1.7602x; 1.0277x over previous
//
#include <hip/hip_runtime.h>

#define NN 100000
#define NNPAD 100352   // 196*512 = 256*392
#define NE 1600000
#define NG 64
#define DI 128
#define DH 256
#define DO 128
#define SEG2 25088     // cmT s-segment per block (~100 KB LDS), NNPAD = 4*SEG2
#define NPART 256
#define PSTRIDE 392    // dst range per partition (256*392 = NNPAD)
#define PCAP 7168      // partition capacity (mean 6250, sd ~79 -> 11 sigma slack)
#define PB 391         // partition blocks: 391*4096 >= NE

using short8 = __attribute__((ext_vector_type(8))) short;
using f32x4  = __attribute__((ext_vector_type(4))) float;

__device__ __forceinline__ float bf2f(unsigned short u) {
    return __uint_as_float(((unsigned)u) << 16);
}
__device__ __forceinline__ unsigned short f2bf(float f) {
    unsigned u = __float_as_uint(f);
    unsigned r = (u + 0x7FFFu + ((u >> 16) & 1u)) >> 16;   // RNE
    return (unsigned short)r;
}

// ---------------- prep + radix partition, merged (independent work) ----------------
__global__ __launch_bounds__(256) void k_prep(const float* __restrict__ x,
        unsigned short* __restrict__ xbf, const float* __restrict__ W1,
        unsigned short* __restrict__ w1t, const int* __restrict__ src,
        const int* __restrict__ dst, int* __restrict__ pcur, int2* __restrict__ pe) {
    int t = threadIdx.x;
    if (blockIdx.x < PB) {
        __shared__ int hist[NPART];
        __shared__ int curb[NPART];
        const int EPT = 16;
        hist[t] = 0;
        __syncthreads();
        int base = blockIdx.x * (256 * EPT) + t;
        int sA[EPT], dA[EPT];
#pragma unroll
        for (int k = 0; k < EPT; ++k) {
            int i = base + k * 256;
            if (i < NE) {
                sA[k] = src[i]; dA[k] = dst[i];
                atomicAdd(&hist[dA[k] / PSTRIDE], 1);
            } else dA[k] = -1;
        }
        __syncthreads();
        curb[t] = t * PCAP + atomicAdd(&pcur[t], hist[t]);
        __syncthreads();
#pragma unroll
        for (int k = 0; k < EPT; ++k) {
            if (dA[k] >= 0) {
                int b = dA[k] / PSTRIDE;
                int pos = atomicAdd(&curb[b], 1);
                pe[pos] = make_int2(sA[k], dA[k]);
            }
        }
        return;
    }
    int i = (blockIdx.x - PB) * 256 + t;
    const int NX4 = NN * 32;
    if (i < NX4) {
        float4 v = ((const float4*)x)[i];
        ushort4 o;
        o.x = f2bf(v.x); o.y = f2bf(v.y); o.z = f2bf(v.z); o.w = f2bf(v.w);
        ((ushort4*)xbf)[i] = o;
    } else if (i < NX4 + DI * DH) {
        int tt = i - NX4;
        int k = tt / DH, n = tt % DH;
        w1t[n * DI + k] = f2bf(W1[tt]);
    }
}

// ---------------- count + partition-local scan + dinv/gdv/cntg ----------------
// rowst gets PARTITION-LOCAL exclusive prefix (finalized in k_place).
__global__ __launch_bounds__(256) void k_count(const int2* __restrict__ pe,
        const int* __restrict__ pcur, const int* __restrict__ batch,
        float* __restrict__ dinv, int2* __restrict__ gdv, int* __restrict__ cntg,
        int* __restrict__ rowst, int* __restrict__ pt) {
    __shared__ int c[512];
    __shared__ int sg[NG];
    int p = blockIdx.x;                 // 256 blocks
    int lo = p * PSTRIDE;
    int t = threadIdx.x;
    c[t] = 0; c[t + 256] = 0;
    if (t < NG) sg[t] = 0;
    __syncthreads();
    int j1 = p * PCAP + pcur[p];
    for (int j = p * PCAP + t; j < j1; j += 256)
        atomicAdd(&c[pe[j].y - lo], 1);
    __syncthreads();
    int cc0 = c[t], cc1 = c[t + 256];
    // inclusive Hillis-Steele over 512 (256 threads x 2 elems)
    for (int off = 1; off < 512; off <<= 1) {
        int v0 = (t >= off) ? c[t - off] : 0;
        int v1 = (t + 256 >= off) ? c[t + 256 - off] : 0;
        __syncthreads();
        c[t] += v0; c[t + 256] += v1;
        __syncthreads();
    }
#pragma unroll
    for (int k = 0; k < 2; ++k) {
        int i = t + k * 256;
        if (i < PSTRIDE) {
            int d = lo + i;
            if (d < NN) {
                int deg = k ? cc1 : cc0;
                float dv = rsqrtf((float)(deg + 1));
                dinv[d] = dv;
                int b = batch[d];
                gdv[d] = make_int2(__float_as_int(dv), b);
                atomicAdd(&sg[b], 1);
                rowst[d] = c[i] - deg;   // partition-local exclusive
            }
        }
    }
    if (t == 0) pt[p] = c[511];
    __syncthreads();
    if (t < NG && sg[t]) atomicAdd(&cntg[t], sg[t]);
}

// ---------------- place: self-scan pt, finalize rowst, CSR fill via LDS cursors ----------------
__global__ __launch_bounds__(256) void k_place(const int2* __restrict__ pe,
        const int* __restrict__ pcur, const int* __restrict__ pt,
        int* __restrict__ rowst, const float* __restrict__ dinv,
        int2* __restrict__ csr8) {
    __shared__ int cur[PSTRIDE];
    __shared__ float dl[PSTRIDE];
    __shared__ int psc[NPART];
    int p = blockIdx.x;                 // 256 blocks
    int lo = p * PSTRIDE;
    int t = threadIdx.x;
    // block-local inclusive scan of the 256 partition totals
    int v = pt[t];
    psc[t] = v;
    __syncthreads();
    for (int off = 1; off < NPART; off <<= 1) {
        int add = (t >= off) ? psc[t - off] : 0;
        __syncthreads();
        psc[t] += add;
        __syncthreads();
    }
    int base = psc[p] - pt[p];          // exclusive prefix for partition p
    for (int i = t; i < PSTRIDE; i += 256) {
        int d = lo + i;
        if (d < NN) {
            int r = rowst[d] + base;
            rowst[d] = r;               // finalize for downstream consumers
            cur[i] = r;
            dl[i]  = dinv[d];
        } else {
            cur[i] = 0; dl[i] = 0.f;
            if (d == NN) rowst[NN] = NE;
        }
    }
    __syncthreads();
    int j1 = p * PCAP + pcur[p];
    for (int j = p * PCAP + t; j < j1; j += 256) {
        int2 ed = pe[j];
        int a = ed.y - lo;
        float w = dinv[ed.x] * dl[a];
        int pos = atomicAdd(&cur[a], 1);
        csr8[pos] = make_int2(ed.x, __float_as_int(w));
    }
}

// ---------------- cmT build: flat streaming over per-graph contiguous (s,w) pairs ----------------
__global__ __launch_bounds__(256) void k_cmbuild(const int2* __restrict__ csr8,
        const int* __restrict__ rowst, const int* __restrict__ batch,
        const int2* __restrict__ gdv, float* __restrict__ cmT) {
    __shared__ float acc[SEG2];          // ~100 KB
    int g   = blockIdx.x >> 2;
    int seg = blockIdx.x & 3;
    int slo = seg * SEG2;
    int t = threadIdx.x;
    for (int i = t; i < SEG2; i += 256) acc[i] = 0.f;

    int lo = 0, hi = NN;
    while (lo < hi) { int m = (lo + hi) >> 1; if (batch[m] < g) lo = m + 1; else hi = m; }
    int dstart = lo;
    int lo2 = lo, hi2 = NN;
    while (lo2 < hi2) { int m = (lo2 + hi2) >> 1; if (batch[m] < g + 1) lo2 = m + 1; else hi2 = m; }
    int e0 = rowst[dstart], e1 = rowst[lo2];
    __syncthreads();

    int j = e0 + t;
    for (; j + 768 < e1; j += 1024) {
        int2 p0 = csr8[j];
        int2 p1 = csr8[j + 256];
        int2 p2 = csr8[j + 512];
        int2 p3 = csr8[j + 768];
        int a0 = p0.x - slo, a1 = p1.x - slo, a2 = p2.x - slo, a3 = p3.x - slo;
        if ((unsigned)a0 < SEG2) atomicAdd(&acc[a0], __int_as_float(p0.y));
        if ((unsigned)a1 < SEG2) atomicAdd(&acc[a1], __int_as_float(p1.y));
        if ((unsigned)a2 < SEG2) atomicAdd(&acc[a2], __int_as_float(p2.y));
        if ((unsigned)a3 < SEG2) atomicAdd(&acc[a3], __int_as_float(p3.y));
    }
    for (; j < e1; j += 256) {
        int2 p = csr8[j];
        int a = p.x - slo;
        if ((unsigned)a < SEG2) atomicAdd(&acc[a], __int_as_float(p.y));
    }
    __syncthreads();

    float* row = cmT + (size_t)g * NNPAD;
    for (int i = t; i < SEG2; i += 256) {
        int s = slo + i;
        float v = acc[i];
        if (s < NN) {
            int2 gv = gdv[s];
            if (gv.y == g) { float dv = __int_as_float(gv.x); v += dv * dv; }
        }
        row[s] = v;
    }
}

// ---------------- layer-1 aggregation: packed CSR, 4-way unroll (R15-proven) ----------------
__global__ __launch_bounds__(256) void k_agg16(const unsigned short* __restrict__ feat,
        const int2* __restrict__ csr8, const int* __restrict__ row_start,
        const float* __restrict__ dinv, unsigned short* __restrict__ out, int n) {
    int gid = blockIdx.x * blockDim.x + threadIdx.x;
    int node = gid >> 4;
    int lane = threadIdx.x & 15;
    if (node >= n) return;
    const short8* f8 = (const short8*)feat;
    float wd = dinv[node];
    float wd2 = wd * wd;
    short8 a = f8[(size_t)node * 16 + lane];
    float acc[8];
#pragma unroll
    for (int i = 0; i < 8; ++i) acc[i] = bf2f((unsigned short)a[i]) * wd2;
    int j = row_start[node], end = row_start[node + 1];
    for (; j + 3 < end; j += 4) {
        int2 p0 = csr8[j], p1 = csr8[j + 1], p2 = csr8[j + 2], p3 = csr8[j + 3];
        float w0 = __int_as_float(p0.y), w1 = __int_as_float(p1.y);
        float w2 = __int_as_float(p2.y), w3 = __int_as_float(p3.y);
        short8 v0 = f8[(size_t)p0.x * 16 + lane];
        short8 v1 = f8[(size_t)p1.x * 16 + lane];
        short8 v2 = f8[(size_t)p2.x * 16 + lane];
        short8 v3 = f8[(size_t)p3.x * 16 + lane];
#pragma unroll
        for (int i = 0; i < 8; ++i)
            acc[i] += w0 * bf2f((unsigned short)v0[i]) + w1 * bf2f((unsigned short)v1[i])
                    + w2 * bf2f((unsigned short)v2[i]) + w3 * bf2f((unsigned short)v3[i]);
    }
    for (; j < end; ++j) {
        int2 p = csr8[j];
        float w = __int_as_float(p.y);
        short8 v = f8[(size_t)p.x * 16 + lane];
#pragma unroll
        for (int i = 0; i < 8; ++i) acc[i] += w * bf2f((unsigned short)v[i]);
    }
    short8 o;
#pragma unroll
    for (int i = 0; i < 8; ++i) o[i] = (short)f2bf(acc[i]);
    ((short8*)out)[(size_t)node * 16 + lane] = o;
}

// ---------------- fused: h1-chunk MFMA (LDS) + pre-partial MFMA ----------------
__global__ __launch_bounds__(512) void k_fused(const unsigned short* __restrict__ agg1,
        const unsigned short* __restrict__ w1t, const float* __restrict__ b1,
        const float* __restrict__ cmT, float* __restrict__ partial) {
    __shared__ unsigned short Ws[256 * 128];  // 64 KB
    __shared__ unsigned short As[64 * 128];   // 16 KB
    __shared__ unsigned short Hs[256 * 64];   // 32 KB
    __shared__ unsigned short Cs[64 * 64];    // 8 KB

    const int tid = threadIdx.x;
    const int sb = blockIdx.x * 512;

#pragma unroll
    for (int i = 0; i < 8; ++i) {
        int c = tid + i * 512;
        int row = c >> 4, seg = c & 15;
        uint4 v = *(const uint4*)(w1t + row * 128 + seg * 8);
        *(uint4*)((char*)Ws + row * 256 + ((seg * 16) ^ ((row & 7) << 4))) = v;
    }

    const int w  = tid >> 6;
    const int l  = tid & 63;
    const int lr = l & 15;
    const int lg = l >> 4;
    const int swz = (lr & 7) << 4;
    const int j0 = w * 32;

    float bb0 = b1[j0 + lr];
    float bb1 = b1[j0 + 16 + lr];

    f32x4 acc2[4][2] = {};

    for (int c = 0; c < 8; ++c) {
        int s0 = sb + c * 64;
        __syncthreads();
#pragma unroll
        for (int i = 0; i < 2; ++i) {
            int cc = tid + i * 512;
            int row = cc >> 4, seg = cc & 15;
            uint4 v = make_uint4(0, 0, 0, 0);
            int node = s0 + row;
            if (node < NN) v = *(const uint4*)(agg1 + (size_t)node * 128 + seg * 8);
            *(uint4*)((char*)As + row * 256 + ((seg * 16) ^ ((row & 7) << 4))) = v;
        }
        {
            int g = tid >> 3, seg = tid & 7;
            const float* cp = cmT + (size_t)g * NNPAD + s0 + seg * 8;
            float4 f0 = *(const float4*)cp;
            float4 f1 = *(const float4*)(cp + 4);
            uint4 v;
            v.x = (unsigned)f2bf(f0.x) | ((unsigned)f2bf(f0.y) << 16);
            v.y = (unsigned)f2bf(f0.z) | ((unsigned)f2bf(f0.w) << 16);
            v.z = (unsigned)f2bf(f1.x) | ((unsigned)f2bf(f1.y) << 16);
            v.w = (unsigned)f2bf(f1.z) | ((unsigned)f2bf(f1.w) << 16);
            *(uint4*)((char*)Cs + g * 128 + ((seg * 16) ^ ((g & 7) << 4))) = v;
        }
        __syncthreads();

        // phase A: h1 chunk = relu(agg1c @ w1t^T + b1), K=128
        f32x4 accA[4][2] = {};
#pragma unroll
        for (int ks = 0; ks < 4; ++ks) {
            int kb = ks * 64 + lg * 16;
            short8 a[4];
#pragma unroll
            for (int m = 0; m < 4; ++m)
                a[m] = *(const short8*)((const char*)As + (m * 16 + lr) * 256 + (kb ^ swz));
#pragma unroll
            for (int n = 0; n < 2; ++n) {
                short8 b = *(const short8*)((const char*)Ws + (j0 + n * 16 + lr) * 256 + (kb ^ swz));
#pragma unroll
                for (int m = 0; m < 4; ++m)
                    accA[m][n] = __builtin_amdgcn_mfma_f32_16x16x32_bf16(a[m], b, accA[m][n], 0, 0, 0);
            }
        }
#pragma unroll
        for (int n = 0; n < 2; ++n) {
            int j = j0 + n * 16 + lr;
            float bbv = n ? bb1 : bb0;
#pragma unroll
            for (int m = 0; m < 4; ++m) {
                float v0 = fmaxf(accA[m][n][0] + bbv, 0.f);
                float v1 = fmaxf(accA[m][n][1] + bbv, 0.f);
                float v2 = fmaxf(accA[m][n][2] + bbv, 0.f);
                float v3 = fmaxf(accA[m][n][3] + bbv, 0.f);
                uint2 p;
                p.x = (unsigned)f2bf(v0) | ((unsigned)f2bf(v1) << 16);
                p.y = (unsigned)f2bf(v2) | ((unsigned)f2bf(v3) << 16);
                *(uint2*)((char*)Hs + j * 128 + (((m * 16 + lg * 4) * 2) ^ swz)) = p;
            }
        }
        __syncthreads();

        // phase B: acc2[g][j] += Cs @ Hs^T, K=64
#pragma unroll
        for (int ks = 0; ks < 2; ++ks) {
            int kb = ks * 64 + lg * 16;
            short8 a[4];
#pragma unroll
            for (int mg = 0; mg < 4; ++mg)
                a[mg] = *(const short8*)((const char*)Cs + (mg * 16 + lr) * 128 + (kb ^ swz));
#pragma unroll
            for (int n = 0; n < 2; ++n) {
                short8 b = *(const short8*)((const char*)Hs + (j0 + n * 16 + lr) * 128 + (kb ^ swz));
#pragma unroll
                for (int mg = 0; mg < 4; ++mg)
                    acc2[mg][n] = __builtin_amdgcn_mfma_f32_16x16x32_bf16(a[mg], b, acc2[mg][n], 0, 0, 0);
            }
        }
    }

    float* pb = partial + (size_t)blockIdx.x * (NG * DH);
#pragma unroll
    for (int mg = 0; mg < 4; ++mg)
#pragma unroll
        for (int n = 0; n < 2; ++n)
#pragma unroll
            for (int r = 0; r < 4; ++r) {
                int g = mg * 16 + lg * 4 + r;
                int j = j0 + n * 16 + lr;
                pb[g * DH + j] = acc2[mg][n][r];
            }
}

// ---------------- tail: reduce 196 partials + final 64x256x128 GEMM ----------------
__global__ __launch_bounds__(256) void k_tail(const float* __restrict__ partial,
        const float* __restrict__ W2, const float* __restrict__ b2,
        const int* __restrict__ cntg, float* __restrict__ out) {
    __shared__ float pre[DH];
    int g = blockIdx.x;
    int t = threadIdx.x;
    float s0 = 0.f, s1 = 0.f, s2 = 0.f, s3 = 0.f;
    for (int b = 0; b < 196; b += 4) {
        s0 += partial[(size_t)b * (NG * DH) + g * DH + t];
        s1 += partial[(size_t)(b + 1) * (NG * DH) + g * DH + t];
        s2 += partial[(size_t)(b + 2) * (NG * DH) + g * DH + t];
        s3 += partial[(size_t)(b + 3) * (NG * DH) + g * DH + t];
    }
    pre[t] = (s0 + s1) + (s2 + s3);
    __syncthreads();
    if (t < DO) {
        float acc = (float)cntg[g] * b2[t];
        for (int k = 0; k < DH; ++k)
            acc = fmaf(pre[k], W2[k * DO + t], acc);
        out[g * DO + t] = acc;
    }
}

// ---------------- launch ----------------

extern "C" void kernel_launch(void* const* d_in, const int* in_sizes, int n_in,
                              void* d_out, int out_size, void* d_ws, size_t ws_size,
                              hipStream_t stream) {
    const float* x     = (const float*)d_in[0];
    const int*   ei    = (const int*)d_in[1];
    const int*   batch = (const int*)d_in[2];
    const float* W1    = (const float*)d_in[3];
    const float* b1    = (const float*)d_in[4];
    const float* W2    = (const float*)d_in[5];
    const float* b2    = (const float*)d_in[6];
    float* out = (float*)d_out;

    const int* src = ei;
    const int* dst = ei + NE;

    // workspace layout, peak ~120 MB
    char* ws = (char*)d_ws;
    float*          dinv    = (float*)(ws + 0);                  // 400 KB
    int*            rowst   = (int*)(ws + 1048576);              // NN+1
    int*            pt      = (int*)(ws + 1572864);              // 1 KB partition totals
    unsigned short* w1t     = (unsigned short*)(ws + 1577216);   // 64 KB
    int2*           gdv     = (int2*)(ws + 1642752);             // 800 KB
    int2*           csr8    = (int2*)(ws + 2443264);             // 12.8 MB
    unsigned short* xbf     = (unsigned short*)(ws + 15243264);  // 25.6 MB
    unsigned short* agg1    = (unsigned short*)(ws + 40843264);  // 25.6 MB
    float*          cmT     = (float*)(ws + 66443264);           // 25.69 MB
    float*          partial = (float*)(ws + 92133376);           // 12.85 MB
    int2*           pe      = (int2*)(ws + 104978432);           // 14.68 MB
    int*            pcur    = (int*)(ws + 119658496);            // 1 KB
    int*            cntg    = (int*)(ws + 119659520);            // 256 B (adjacent to pcur)

    const int BLK = 256;
    auto cdiv = [](int a, int b) { return (a + b - 1) / b; };

    // ---- zero partition cursors + graph counts (single contiguous memset) ----
    hipMemsetAsync(pcur, 0, NPART * 4 + NG * 4, stream);

    // ---- prep (cvt + wt) merged with radix partition ----
    {
        int prep_blocks = cdiv(NN * 32 + DI * DH, BLK);
        k_prep<<<PB + prep_blocks, BLK, 0, stream>>>(x, xbf, W1, w1t, src, dst, pcur, pe);
    }

    // ---- count + local prefix + dinv/gdv/cntg ----
    k_count<<<NPART, 256, 0, stream>>>(pe, pcur, batch, dinv, gdv, cntg, rowst, pt);

    // ---- place: self-scan pt, finalize rowst, CSR fill ----
    k_place<<<NPART, 256, 0, stream>>>(pe, pcur, pt, rowst, dinv, csr8);

    // ---- cmT from packed CSR (flat streaming, LDS-accumulated) ----
    k_cmbuild<<<NG * 4, 256, 0, stream>>>(csr8, rowst, batch, gdv, cmT);

    // ---- layer 1 aggregation ----
    k_agg16<<<cdiv(NN * 16, BLK), BLK, 0, stream>>>(xbf, csr8, rowst, dinv, agg1, NN);

    // ---- fused h1 + pre-partials (MFMA) ----
    k_fused<<<NNPAD / 512, 512, 0, stream>>>(agg1, w1t, b1, cmT, partial);

    // ---- tail ----
    k_tail<<<NG, 256, 0, stream>>>(partial, W2, b2, cntg, out);
}